// Round 1
// baseline (5120.145 us; speedup 1.0000x reference)
//
#include <hip/hip_runtime.h>

// LightGCN on MI355X — round 0 baseline (atomic scatter).
// N = 150000 nodes, E = 2M edges, D = 64, L = 3 layers.

#define N_NODES 150000
#define N_EDGES 2000000
#define DIM     64
#define N_LAYERS 3

__global__ void zero_f32(float* __restrict__ p, int n) {
    int i = blockIdx.x * blockDim.x + threadIdx.x;
    if (i < n) p[i] = 0.0f;
}

__global__ void zero_f32_vec4(float4* __restrict__ p, int n4) {
    int i = blockIdx.x * blockDim.x + threadIdx.x;
    if (i < n4) p[i] = make_float4(0.f, 0.f, 0.f, 0.f);
}

__global__ void degree_kernel(const int* __restrict__ dst, float* __restrict__ deg) {
    int e = blockIdx.x * blockDim.x + threadIdx.x;
    if (e < N_EDGES) atomicAdd(&deg[dst[e]], 1.0f);
}

__global__ void dinv_kernel(float* __restrict__ deg) {
    int i = blockIdx.x * blockDim.x + threadIdx.x;
    if (i < N_NODES) {
        float d = deg[i];
        deg[i] = (d > 0.0f) ? (1.0f / sqrtf(d)) : 0.0f;
    }
}

// Copy emb -> x_cur and acc(d_out), float4-vectorized.
__global__ void init_kernel(const float4* __restrict__ emb,
                            float4* __restrict__ x_cur,
                            float4* __restrict__ acc, int n4) {
    int i = blockIdx.x * blockDim.x + threadIdx.x;
    if (i < n4) {
        float4 v = emb[i];
        x_cur[i] = v;
        acc[i]   = v;
    }
}

// One edge handled by 16 consecutive threads, each owning one float4 (4 dims).
__global__ void spmm_scatter(const int* __restrict__ src,
                             const int* __restrict__ dst,
                             const float* __restrict__ dinv,
                             const float* __restrict__ x,
                             float* __restrict__ y) {
    long long gid = (long long)blockIdx.x * blockDim.x + threadIdx.x;
    int e = (int)(gid >> 4);
    int q = (int)(gid & 15);
    if (e >= N_EDGES) return;
    int s = src[e];
    int d = dst[e];
    float w = dinv[s] * dinv[d];
    const float4 v = *reinterpret_cast<const float4*>(x + (size_t)s * DIM + q * 4);
    float* out = y + (size_t)d * DIM + q * 4;
    atomicAdd(out + 0, v.x * w);
    atomicAdd(out + 1, v.y * w);
    atomicAdd(out + 2, v.z * w);
    atomicAdd(out + 3, v.w * w);
}

// acc += x, float4-vectorized.
__global__ void acc_kernel(float4* __restrict__ acc, const float4* __restrict__ x, int n4) {
    int i = blockIdx.x * blockDim.x + threadIdx.x;
    if (i < n4) {
        float4 a = acc[i];
        float4 v = x[i];
        a.x += v.x; a.y += v.y; a.z += v.z; a.w += v.w;
        acc[i] = a;
    }
}

__global__ void scale_kernel(float4* __restrict__ acc, float s, int n4) {
    int i = blockIdx.x * blockDim.x + threadIdx.x;
    if (i < n4) {
        float4 a = acc[i];
        a.x *= s; a.y *= s; a.z *= s; a.w *= s;
        acc[i] = a;
    }
}

extern "C" void kernel_launch(void* const* d_in, const int* in_sizes, int n_in,
                              void* d_out, int out_size, void* d_ws, size_t ws_size,
                              hipStream_t stream) {
    const int*   edge = (const int*)d_in[0];
    const int*   src  = edge;
    const int*   dst  = edge + N_EDGES;
    const float* emb  = (const float*)d_in[1];
    float* out = (float*)d_out;

    char* ws = (char*)d_ws;
    float* deg   = (float*)ws;                        // N floats (becomes dinv)
    float* x0    = (float*)(ws + (size_t)N_NODES * 4);  // N*D floats (offset 600000, 16B-aligned)
    float* x1    = x0 + (size_t)N_NODES * DIM;

    const int ND  = N_NODES * DIM;   // 9,600,000
    const int ND4 = ND / 4;          // 2,400,000

    const int B = 256;

    // 1. deg = 0
    zero_f32<<<(N_NODES + B - 1) / B, B, 0, stream>>>(deg, N_NODES);
    // 2. deg[dst[e]] += 1
    degree_kernel<<<(N_EDGES + B - 1) / B, B, 0, stream>>>(dst, deg);
    // 3. deg -> dinv in place
    dinv_kernel<<<(N_NODES + B - 1) / B, B, 0, stream>>>(deg);
    // 4. x_cur = emb; acc = emb
    init_kernel<<<(ND4 + B - 1) / B, B, 0, stream>>>(
        (const float4*)emb, (float4*)x0, (float4*)out, ND4);

    float* x_cur = x0;
    float* x_next = x1;
    for (int l = 0; l < N_LAYERS; ++l) {
        zero_f32_vec4<<<(ND4 + B - 1) / B, B, 0, stream>>>((float4*)x_next, ND4);
        long long total = (long long)N_EDGES * 16;
        spmm_scatter<<<(int)((total + B - 1) / B), B, 0, stream>>>(src, dst, deg, x_cur, x_next);
        acc_kernel<<<(ND4 + B - 1) / B, B, 0, stream>>>((float4*)out, (const float4*)x_next, ND4);
        float* t = x_cur; x_cur = x_next; x_next = t;
    }

    scale_kernel<<<(ND4 + B - 1) / B, B, 0, stream>>>((float4*)out, 1.0f / (N_LAYERS + 1), ND4);
}

// Round 2
// 750.304 us; speedup vs baseline: 6.8241x; 6.8241x over previous
//
#include <hip/hip_runtime.h>

// LightGCN on MI355X — round 1: CSR-by-dst + deterministic gather (no atomics in hot path).
// N = 150000 nodes, E = 2M edges, D = 64, L = 3 layers.

#define N_NODES 150000
#define N_EDGES 2000000
#define DIM     64
#define N_LAYERS 3

__global__ void zero_i32(int* __restrict__ p, int n) {
    int i = blockIdx.x * blockDim.x + threadIdx.x;
    if (i < n) p[i] = 0;
}

// Histogram of in-degrees (int atomics, 2M ops — cheap).
__global__ void hist_kernel(const int* __restrict__ dst, int* __restrict__ cnt) {
    int e = blockIdx.x * blockDim.x + threadIdx.x;
    if (e < N_EDGES) atomicAdd(&cnt[dst[e]], 1);
}

// Single-block exclusive scan of cnt[0..N) -> ptr[0..N], plus ptr[N] = total.
__global__ __launch_bounds__(1024) void scan_kernel(const int* __restrict__ cnt,
                                                    int* __restrict__ ptr) {
    __shared__ int s[1024];
    const int t = threadIdx.x;
    const int CH = (N_NODES + 1023) / 1024;  // 147
    int start = t * CH;
    int end   = start + CH; if (end > N_NODES) end = N_NODES;
    int sum = 0;
    for (int i = start; i < end; ++i) sum += cnt[i];
    s[t] = sum;
    __syncthreads();
    for (int off = 1; off < 1024; off <<= 1) {
        int v = (t >= off) ? s[t - off] : 0;
        __syncthreads();
        s[t] += v;
        __syncthreads();
    }
    int base = s[t] - sum;  // exclusive prefix
    for (int i = start; i < end; ++i) { int c = cnt[i]; ptr[i] = base; base += c; }
    if (t == 1023) ptr[N_NODES] = s[1023];
}

// cursor = ptr copy (scatter cursors); dinv[i] = deg>0 ? 1/sqrt(deg) : 0.
__global__ void prep_kernel(const int* __restrict__ ptr,
                            int* __restrict__ cursor,
                            float* __restrict__ dinv) {
    int i = blockIdx.x * blockDim.x + threadIdx.x;
    if (i < N_NODES) {
        int b = ptr[i], e = ptr[i + 1];
        cursor[i] = b;
        int d = e - b;
        dinv[i] = (d > 0) ? (1.0f / sqrtf((float)d)) : 0.0f;
    }
}

// Scatter edges into CSR buckets; precompute per-edge weight.
__global__ void build_csr(const int* __restrict__ src, const int* __restrict__ dst,
                          const float* __restrict__ dinv,
                          int* __restrict__ cursor,
                          int* __restrict__ csr_src, float* __restrict__ csr_w) {
    int e = blockIdx.x * blockDim.x + threadIdx.x;
    if (e < N_EDGES) {
        int s = src[e], d = dst[e];
        int pos = atomicAdd(&cursor[d], 1);
        csr_src[pos] = s;
        csr_w[pos]   = dinv[s] * dinv[d];
    }
}

__global__ void copy_vec4(const float4* __restrict__ in, float4* __restrict__ out, int n4) {
    int i = blockIdx.x * blockDim.x + threadIdx.x;
    if (i < n4) out[i] = in[i];
}

// One 16-lane group per node; lane q owns dims [4q, 4q+4).
// y_row = sum_j w_j * x[src_j]; acc_row = (acc_row + y_row) * scale; optionally write y.
__global__ void gather_layer(const int* __restrict__ ptr,
                             const int* __restrict__ csr_src,
                             const float* __restrict__ csr_w,
                             const float* __restrict__ xin,
                             float* __restrict__ xout,
                             float* __restrict__ acc,
                             float scale, int writeX) {
    int tid = blockIdx.x * blockDim.x + threadIdx.x;
    int node = tid >> 4;
    int q    = tid & 15;
    if (node >= N_NODES) return;
    int beg = ptr[node], end = ptr[node + 1];
    float4 s = make_float4(0.f, 0.f, 0.f, 0.f);
    for (int j = beg; j < end; ++j) {
        int   sn = csr_src[j];
        float w  = csr_w[j];
        const float4 v = *reinterpret_cast<const float4*>(xin + (size_t)sn * DIM + q * 4);
        s.x += w * v.x; s.y += w * v.y; s.z += w * v.z; s.w += w * v.w;
    }
    size_t off = (size_t)node * DIM + q * 4;
    if (writeX) *reinterpret_cast<float4*>(xout + off) = s;
    float4 a = *reinterpret_cast<const float4*>(acc + off);
    a.x = (a.x + s.x) * scale;
    a.y = (a.y + s.y) * scale;
    a.z = (a.z + s.z) * scale;
    a.w = (a.w + s.w) * scale;
    *reinterpret_cast<float4*>(acc + off) = a;
}

extern "C" void kernel_launch(void* const* d_in, const int* in_sizes, int n_in,
                              void* d_out, int out_size, void* d_ws, size_t ws_size,
                              hipStream_t stream) {
    const int*   edge = (const int*)d_in[0];
    const int*   src  = edge;
    const int*   dst  = edge + N_EDGES;
    const float* emb  = (const float*)d_in[1];
    float* out = (float*)d_out;

    // Workspace layout (all offsets 16B-aligned). Total ~94.6 MB.
    char* ws = (char*)d_ws;
    int*   ptr     = (int*)(ws + 0);                    // 150001 ints (600,004 B; slot 600,064)
    int*   cursor  = (int*)(ws + 600064);               // 150000 ints
    float* dinv    = (float*)(ws + 1200064);            // 150000 floats
    int*   csr_src = (int*)(ws + 1800064);              // 2M ints
    float* csr_w   = (float*)(ws + 9800064);            // 2M floats
    float* x0      = (float*)(ws + 17800064);           // N*D floats
    float* x1      = (float*)(ws + 56200064);           // N*D floats

    const int ND  = N_NODES * DIM;   // 9,600,000
    const int ND4 = ND / 4;          // 2,400,000
    const int B = 256;

    // --- CSR build ---
    zero_i32<<<(N_NODES + B - 1) / B, B, 0, stream>>>(cursor, N_NODES);
    hist_kernel<<<(N_EDGES + B - 1) / B, B, 0, stream>>>(dst, cursor);
    scan_kernel<<<1, 1024, 0, stream>>>(cursor, ptr);
    prep_kernel<<<(N_NODES + B - 1) / B, B, 0, stream>>>(ptr, cursor, dinv);
    build_csr<<<(N_EDGES + B - 1) / B, B, 0, stream>>>(src, dst, dinv, cursor, csr_src, csr_w);

    // --- acc = emb ---
    copy_vec4<<<(ND4 + B - 1) / B, B, 0, stream>>>((const float4*)emb, (float4*)out, ND4);

    // --- 3 propagation layers, acc fused; final layer fuses the /4 scale ---
    const int nodeBlocks = (N_NODES * 16 + B - 1) / B;  // 16 lanes per node
    // layer 0: x0 = A*emb ; acc += x0
    gather_layer<<<nodeBlocks, B, 0, stream>>>(ptr, csr_src, csr_w, emb, x0, out, 1.0f, 1);
    // layer 1: x1 = A*x0 ; acc += x1
    gather_layer<<<nodeBlocks, B, 0, stream>>>(ptr, csr_src, csr_w, x0, x1, out, 1.0f, 1);
    // layer 2: acc = (acc + A*x1) * 0.25 ; no x write needed
    gather_layer<<<nodeBlocks, B, 0, stream>>>(ptr, csr_src, csr_w, x1, nullptr, out,
                                               1.0f / (N_LAYERS + 1), 0);
}

// Round 3
// 547.991 us; speedup vs baseline: 9.3435x; 1.3692x over previous
//
#include <hip/hip_runtime.h>

// LightGCN on MI355X — round 2: parallel scan + fused final combine.
// N = 150000 nodes, E = 2M edges, D = 64, L = 3 layers.

#define N_NODES 150000
#define N_EDGES 2000000
#define DIM     64
#define NB_SCAN 586   // ceil(N_NODES / 256)

__global__ void zero_i32(int* __restrict__ p, int n) {
    int i = blockIdx.x * blockDim.x + threadIdx.x;
    if (i < n) p[i] = 0;
}

// In-degree histogram (int atomics, 2M ops).
__global__ void hist_kernel(const int* __restrict__ dst, int* __restrict__ cnt) {
    int e = blockIdx.x * blockDim.x + threadIdx.x;
    if (e < N_EDGES) atomicAdd(&cnt[dst[e]], 1);
}

// Scan pass 1: per-block (256-element) sums of cnt.
__global__ void scan_blocksum(const int* __restrict__ cnt, int* __restrict__ bsum) {
    __shared__ int s[256];
    int t = threadIdx.x;
    int i = blockIdx.x * 256 + t;
    s[t] = (i < N_NODES) ? cnt[i] : 0;
    __syncthreads();
    for (int off = 128; off > 0; off >>= 1) {
        if (t < off) s[t] += s[t + off];
        __syncthreads();
    }
    if (t == 0) bsum[blockIdx.x] = s[0];
}

// Scan pass 2: exclusive scan of the 586 block sums (one block); also ptr[N] = total.
__global__ __launch_bounds__(1024) void scan_bsum(int* __restrict__ bsum, int* __restrict__ ptrN) {
    __shared__ int s[1024];
    int t = threadIdx.x;
    int v = (t < NB_SCAN) ? bsum[t] : 0;
    s[t] = v;
    __syncthreads();
    for (int off = 1; off < 1024; off <<= 1) {
        int u = (t >= off) ? s[t - off] : 0;
        __syncthreads();
        s[t] += u;
        __syncthreads();
    }
    if (t < NB_SCAN) bsum[t] = s[t] - v;   // exclusive prefix
    if (t == 1023) *ptrN = s[1023];        // total == N_EDGES
}

// Scan pass 3: per-block exclusive scan + block offset -> ptr & cursor; dinv fused.
// NOTE: cursor may alias cnt (each thread reads cnt[i] before any write to cursor[i]).
__global__ void scan_final(const int* __restrict__ cnt, const int* __restrict__ bsum,
                           int* __restrict__ ptr, int* __restrict__ cursor,
                           float* __restrict__ dinv) {
    __shared__ int s[256];
    int t = threadIdx.x;
    int i = blockIdx.x * 256 + t;
    int v = (i < N_NODES) ? cnt[i] : 0;
    s[t] = v;
    __syncthreads();
    for (int off = 1; off < 256; off <<= 1) {
        int u = (t >= off) ? s[t - off] : 0;
        __syncthreads();
        s[t] += u;
        __syncthreads();
    }
    if (i < N_NODES) {
        int ex = bsum[blockIdx.x] + s[t] - v;
        ptr[i]    = ex;
        cursor[i] = ex;
        dinv[i]   = (v > 0) ? (1.0f / sqrtf((float)v)) : 0.0f;
    }
}

// Scatter edges into CSR buckets; precompute per-edge weight.
__global__ void build_csr(const int* __restrict__ src, const int* __restrict__ dst,
                          const float* __restrict__ dinv,
                          int* __restrict__ cursor,
                          int* __restrict__ csr_src, float* __restrict__ csr_w) {
    int e = blockIdx.x * blockDim.x + threadIdx.x;
    if (e < N_EDGES) {
        int s = src[e], d = dst[e];
        int pos = atomicAdd(&cursor[d], 1);
        csr_src[pos] = s;
        csr_w[pos]   = dinv[s] * dinv[d];
    }
}

// One 16-lane group per node; lane q owns dims [4q, 4q+4). xout = A * xin (row).
__global__ void gather_layer(const int* __restrict__ ptr,
                             const int* __restrict__ csr_src,
                             const float* __restrict__ csr_w,
                             const float* __restrict__ xin,
                             float* __restrict__ xout) {
    int tid = blockIdx.x * blockDim.x + threadIdx.x;
    int node = tid >> 4;
    int q    = tid & 15;
    if (node >= N_NODES) return;
    int beg = ptr[node], end = ptr[node + 1];
    float4 s = make_float4(0.f, 0.f, 0.f, 0.f);
    for (int j = beg; j < end; ++j) {
        int   sn = csr_src[j];
        float w  = csr_w[j];
        const float4 v = *reinterpret_cast<const float4*>(xin + (size_t)sn * DIM + q * 4);
        s.x += w * v.x; s.y += w * v.y; s.z += w * v.z; s.w += w * v.w;
    }
    *reinterpret_cast<float4*>(xout + (size_t)node * DIM + q * 4) = s;
}

// Final layer fused with the 4-state average: out = (emb + x0 + x1 + A*x1) / 4.
__global__ void gather_final(const int* __restrict__ ptr,
                             const int* __restrict__ csr_src,
                             const float* __restrict__ csr_w,
                             const float* __restrict__ x1,   // layer-2 input
                             const float* __restrict__ emb,
                             const float* __restrict__ x0,
                             float* __restrict__ out) {
    int tid = blockIdx.x * blockDim.x + threadIdx.x;
    int node = tid >> 4;
    int q    = tid & 15;
    if (node >= N_NODES) return;
    int beg = ptr[node], end = ptr[node + 1];
    float4 s = make_float4(0.f, 0.f, 0.f, 0.f);
    for (int j = beg; j < end; ++j) {
        int   sn = csr_src[j];
        float w  = csr_w[j];
        const float4 v = *reinterpret_cast<const float4*>(x1 + (size_t)sn * DIM + q * 4);
        s.x += w * v.x; s.y += w * v.y; s.z += w * v.z; s.w += w * v.w;
    }
    size_t off = (size_t)node * DIM + q * 4;
    const float4 e0 = *reinterpret_cast<const float4*>(emb + off);
    const float4 a0 = *reinterpret_cast<const float4*>(x0 + off);
    const float4 b0 = *reinterpret_cast<const float4*>(x1 + off);
    float4 r;
    r.x = (e0.x + a0.x + b0.x + s.x) * 0.25f;
    r.y = (e0.y + a0.y + b0.y + s.y) * 0.25f;
    r.z = (e0.z + a0.z + b0.z + s.z) * 0.25f;
    r.w = (e0.w + a0.w + b0.w + s.w) * 0.25f;
    *reinterpret_cast<float4*>(out + off) = r;
}

extern "C" void kernel_launch(void* const* d_in, const int* in_sizes, int n_in,
                              void* d_out, int out_size, void* d_ws, size_t ws_size,
                              hipStream_t stream) {
    const int*   edge = (const int*)d_in[0];
    const int*   src  = edge;
    const int*   dst  = edge + N_EDGES;
    const float* emb  = (const float*)d_in[1];
    float* out = (float*)d_out;

    // Workspace layout (16B-aligned offsets). Total ~94.6 MB (same as round 1).
    char* ws = (char*)d_ws;
    int*   ptr     = (int*)(ws + 0);          // N+1 ints
    int*   cnt     = (int*)(ws + 600064);     // N ints (reused as cursor)
    float* dinv    = (float*)(ws + 1200064);  // N floats
    int*   bsum    = (int*)(ws + 1800064);    // NB_SCAN ints
    int*   csr_src = (int*)(ws + 1802432);    // E ints
    float* csr_w   = (float*)(ws + 9802432);  // E floats
    float* x0      = (float*)(ws + 17802432); // N*D floats
    float* x1      = (float*)(ws + 56202432); // N*D floats

    const int B = 256;
    int* cursor = cnt;  // alias — see scan_final note

    // --- CSR build ---
    zero_i32<<<(N_NODES + B - 1) / B, B, 0, stream>>>(cnt, N_NODES);
    hist_kernel<<<(N_EDGES + B - 1) / B, B, 0, stream>>>(dst, cnt);
    scan_blocksum<<<NB_SCAN, B, 0, stream>>>(cnt, bsum);
    scan_bsum<<<1, 1024, 0, stream>>>(bsum, ptr + N_NODES);
    scan_final<<<NB_SCAN, B, 0, stream>>>(cnt, bsum, ptr, cursor, dinv);
    build_csr<<<(N_EDGES + B - 1) / B, B, 0, stream>>>(src, dst, dinv, cursor, csr_src, csr_w);

    // --- 3 propagation layers ---
    const int nodeBlocks = (N_NODES * 16 + B - 1) / B;  // 16 lanes per node
    gather_layer<<<nodeBlocks, B, 0, stream>>>(ptr, csr_src, csr_w, emb, x0);   // x0 = A*emb
    gather_layer<<<nodeBlocks, B, 0, stream>>>(ptr, csr_src, csr_w, x0, x1);    // x1 = A*x0
    gather_final<<<nodeBlocks, B, 0, stream>>>(ptr, csr_src, csr_w, x1, emb, x0, out);
}

// Round 4
// 489.816 us; speedup vs baseline: 10.4532x; 1.1188x over previous
//
#include <hip/hip_runtime.h>
#include <hip/hip_fp16.h>

// LightGCN on MI355X — round 3: weight-free y-space propagation + fp16 intermediates.
// y_l = dinv .* x_l  =>  z_{l+1}[d] = sum_{s in in(d)} y_l[s]  (unweighted gather)
//                        y_{l+1}    = dinv^2 .* z_{l+1},   x_l = sqrt(deg) .* y_l
// out = (emb + x1 + x2 + x3)/4 = 0.25*(emb + sq.*(y1+y2) + dinv.*z3)

#define N_NODES 150000
#define N_EDGES 2000000
#define DIM     64
#define NB_SCAN 586   // ceil(N_NODES / 256)

__global__ void zero_i32(int* __restrict__ p, int n) {
    int i = blockIdx.x * blockDim.x + threadIdx.x;
    if (i < n) p[i] = 0;
}

__global__ void hist_kernel(const int* __restrict__ dst, int* __restrict__ cnt) {
    int e = blockIdx.x * blockDim.x + threadIdx.x;
    if (e < N_EDGES) atomicAdd(&cnt[dst[e]], 1);
}

__global__ void scan_blocksum(const int* __restrict__ cnt, int* __restrict__ bsum) {
    __shared__ int s[256];
    int t = threadIdx.x;
    int i = blockIdx.x * 256 + t;
    s[t] = (i < N_NODES) ? cnt[i] : 0;
    __syncthreads();
    for (int off = 128; off > 0; off >>= 1) {
        if (t < off) s[t] += s[t + off];
        __syncthreads();
    }
    if (t == 0) bsum[blockIdx.x] = s[0];
}

__global__ __launch_bounds__(1024) void scan_bsum(int* __restrict__ bsum, int* __restrict__ ptrN) {
    __shared__ int s[1024];
    int t = threadIdx.x;
    int v = (t < NB_SCAN) ? bsum[t] : 0;
    s[t] = v;
    __syncthreads();
    for (int off = 1; off < 1024; off <<= 1) {
        int u = (t >= off) ? s[t - off] : 0;
        __syncthreads();
        s[t] += u;
        __syncthreads();
    }
    if (t < NB_SCAN) bsum[t] = s[t] - v;
    if (t == 1023) *ptrN = s[1023];
}

// Per-block exclusive scan + offset -> ptr & cursor; dinv fused. cursor aliases cnt.
__global__ void scan_final(const int* __restrict__ cnt, const int* __restrict__ bsum,
                           int* __restrict__ ptr, int* __restrict__ cursor,
                           float* __restrict__ dinv) {
    __shared__ int s[256];
    int t = threadIdx.x;
    int i = blockIdx.x * 256 + t;
    int v = (i < N_NODES) ? cnt[i] : 0;
    s[t] = v;
    __syncthreads();
    for (int off = 1; off < 256; off <<= 1) {
        int u = (t >= off) ? s[t - off] : 0;
        __syncthreads();
        s[t] += u;
        __syncthreads();
    }
    if (i < N_NODES) {
        int ex = bsum[blockIdx.x] + s[t] - v;
        ptr[i]    = ex;
        cursor[i] = ex;
        dinv[i]   = (v > 0) ? (1.0f / sqrtf((float)v)) : 0.0f;
    }
}

// Scatter edges into CSR buckets (src index only — weights are gone).
__global__ void build_csr(const int* __restrict__ src, const int* __restrict__ dst,
                          int* __restrict__ cursor, int* __restrict__ csr_src) {
    int e = blockIdx.x * blockDim.x + threadIdx.x;
    if (e < N_EDGES) {
        int s = src[e], d = dst[e];
        int pos = atomicAdd(&cursor[d], 1);
        csr_src[pos] = s;
    }
}

// y0 = dinv .* emb, stored fp16. One thread per 8 dims.
__global__ void init_y0(const float* __restrict__ emb, const float* __restrict__ dinv,
                        __half* __restrict__ y0) {
    int i = blockIdx.x * blockDim.x + threadIdx.x;
    if (i >= N_NODES * 8) return;
    int node = i >> 3, q = i & 7;
    float dv = dinv[node];
    size_t off = ((size_t)node << 6) + (q << 3);
    const float4 e0 = *reinterpret_cast<const float4*>(emb + off);
    const float4 e1 = *reinterpret_cast<const float4*>(emb + off + 4);
    uint4 o;
    __half2* oh = reinterpret_cast<__half2*>(&o);
    oh[0] = __float22half2_rn(make_float2(e0.x * dv, e0.y * dv));
    oh[1] = __float22half2_rn(make_float2(e0.z * dv, e0.w * dv));
    oh[2] = __float22half2_rn(make_float2(e1.x * dv, e1.y * dv));
    oh[3] = __float22half2_rn(make_float2(e1.z * dv, e1.w * dv));
    *reinterpret_cast<uint4*>(y0 + off) = o;
}

// One 8-lane group per node; lane q owns dims [8q, 8q+8).
// z = sum of yin rows; yout = (half)(dinv^2 * z).
__global__ void gather_layer_h(const int* __restrict__ ptr,
                               const int* __restrict__ csr_src,
                               const float* __restrict__ dinv,
                               const __half* __restrict__ yin,
                               __half* __restrict__ yout) {
    int tid = blockIdx.x * blockDim.x + threadIdx.x;
    int node = tid >> 3;
    int q    = tid & 7;
    if (node >= N_NODES) return;
    int beg = ptr[node], end = ptr[node + 1];
    float a[8] = {0.f, 0.f, 0.f, 0.f, 0.f, 0.f, 0.f, 0.f};
    for (int j = beg; j < end; ++j) {
        int sn = csr_src[j];
        const uint4 v = *reinterpret_cast<const uint4*>(yin + ((size_t)sn << 6) + (q << 3));
        const __half2* h = reinterpret_cast<const __half2*>(&v);
        float2 f;
        f = __half22float2(h[0]); a[0] += f.x; a[1] += f.y;
        f = __half22float2(h[1]); a[2] += f.x; a[3] += f.y;
        f = __half22float2(h[2]); a[4] += f.x; a[5] += f.y;
        f = __half22float2(h[3]); a[6] += f.x; a[7] += f.y;
    }
    float dv = dinv[node];
    float w = dv * dv;
    uint4 o;
    __half2* oh = reinterpret_cast<__half2*>(&o);
    oh[0] = __float22half2_rn(make_float2(a[0] * w, a[1] * w));
    oh[1] = __float22half2_rn(make_float2(a[2] * w, a[3] * w));
    oh[2] = __float22half2_rn(make_float2(a[4] * w, a[5] * w));
    oh[3] = __float22half2_rn(make_float2(a[6] * w, a[7] * w));
    *reinterpret_cast<uint4*>(yout + ((size_t)node << 6) + (q << 3)) = o;
}

// Final: z3 gather from y2; out = 0.25*(emb + sq*(y1+y2) + dinv*z3), fp32.
__global__ void gather_final_h(const int* __restrict__ ptr,
                               const int* __restrict__ csr_src,
                               const float* __restrict__ dinv,
                               const __half* __restrict__ y2,   // layer-3 gather input
                               const __half* __restrict__ y1,
                               const float* __restrict__ emb,
                               float* __restrict__ out) {
    int tid = blockIdx.x * blockDim.x + threadIdx.x;
    int node = tid >> 3;
    int q    = tid & 7;
    if (node >= N_NODES) return;
    int beg = ptr[node], end = ptr[node + 1];
    float a[8] = {0.f, 0.f, 0.f, 0.f, 0.f, 0.f, 0.f, 0.f};
    for (int j = beg; j < end; ++j) {
        int sn = csr_src[j];
        const uint4 v = *reinterpret_cast<const uint4*>(y2 + ((size_t)sn << 6) + (q << 3));
        const __half2* h = reinterpret_cast<const __half2*>(&v);
        float2 f;
        f = __half22float2(h[0]); a[0] += f.x; a[1] += f.y;
        f = __half22float2(h[1]); a[2] += f.x; a[3] += f.y;
        f = __half22float2(h[2]); a[4] += f.x; a[5] += f.y;
        f = __half22float2(h[3]); a[6] += f.x; a[7] += f.y;
    }
    float dv = dinv[node];
    float sq = (dv > 0.f) ? (1.0f / dv) : 0.0f;   // sqrt(deg), 0 for deg-0

    size_t off = ((size_t)node << 6) + (q << 3);
    const float4 e0 = *reinterpret_cast<const float4*>(emb + off);
    const float4 e1 = *reinterpret_cast<const float4*>(emb + off + 4);
    const uint4 v1 = *reinterpret_cast<const uint4*>(y1 + off);
    const uint4 v2 = *reinterpret_cast<const uint4*>(y2 + off);
    const __half2* h1 = reinterpret_cast<const __half2*>(&v1);
    const __half2* h2 = reinterpret_cast<const __half2*>(&v2);

    float e[8] = {e0.x, e0.y, e0.z, e0.w, e1.x, e1.y, e1.z, e1.w};
    float r[8];
#pragma unroll
    for (int k = 0; k < 4; ++k) {
        float2 f1 = __half22float2(h1[k]);
        float2 f2 = __half22float2(h2[k]);
        r[2 * k]     = 0.25f * (e[2 * k]     + sq * (f1.x + f2.x) + dv * a[2 * k]);
        r[2 * k + 1] = 0.25f * (e[2 * k + 1] + sq * (f1.y + f2.y) + dv * a[2 * k + 1]);
    }
    float4 o0 = make_float4(r[0], r[1], r[2], r[3]);
    float4 o1 = make_float4(r[4], r[5], r[6], r[7]);
    *reinterpret_cast<float4*>(out + off)     = o0;
    *reinterpret_cast<float4*>(out + off + 4) = o1;
}

extern "C" void kernel_launch(void* const* d_in, const int* in_sizes, int n_in,
                              void* d_out, int out_size, void* d_ws, size_t ws_size,
                              hipStream_t stream) {
    const int*   edge = (const int*)d_in[0];
    const int*   src  = edge;
    const int*   dst  = edge + N_EDGES;
    const float* emb  = (const float*)d_in[1];
    float* out = (float*)d_out;

    // Workspace layout (16B-aligned). Total ~67.4 MB.
    char* ws = (char*)d_ws;
    int*    ptr     = (int*)(ws + 0);          // N+1 ints
    int*    cnt     = (int*)(ws + 600064);     // N ints (reused as cursor)
    float*  dinv    = (float*)(ws + 1200064);  // N floats
    int*    bsum    = (int*)(ws + 1800064);    // NB_SCAN ints
    int*    csr_src = (int*)(ws + 1802432);    // E ints
    __half* y0      = (__half*)(ws + 9802432);  // N*D halves
    __half* y1      = (__half*)(ws + 29002432); // N*D halves
    __half* y2      = (__half*)(ws + 48202432); // N*D halves

    const int B = 256;
    int* cursor = cnt;

    // --- CSR build ---
    zero_i32<<<(N_NODES + B - 1) / B, B, 0, stream>>>(cnt, N_NODES);
    hist_kernel<<<(N_EDGES + B - 1) / B, B, 0, stream>>>(dst, cnt);
    scan_blocksum<<<NB_SCAN, B, 0, stream>>>(cnt, bsum);
    scan_bsum<<<1, 1024, 0, stream>>>(bsum, ptr + N_NODES);
    scan_final<<<NB_SCAN, B, 0, stream>>>(cnt, bsum, ptr, cursor, dinv);
    build_csr<<<(N_EDGES + B - 1) / B, B, 0, stream>>>(src, dst, cursor, csr_src);

    // --- y0 = dinv .* emb ---
    const int NT8 = N_NODES * 8;
    init_y0<<<(NT8 + B - 1) / B, B, 0, stream>>>(emb, dinv, y0);

    // --- 3 propagation layers (8 lanes per node) ---
    const int nodeBlocks = (NT8 + B - 1) / B;
    gather_layer_h<<<nodeBlocks, B, 0, stream>>>(ptr, csr_src, dinv, y0, y1);  // y1 (x1)
    gather_layer_h<<<nodeBlocks, B, 0, stream>>>(ptr, csr_src, dinv, y1, y2);  // y2 (x2)
    gather_final_h<<<nodeBlocks, B, 0, stream>>>(ptr, csr_src, dinv, y2, y1, emb, out);
}

// Round 5
// 475.543 us; speedup vs baseline: 10.7669x; 1.0300x over previous
//
#include <hip/hip_runtime.h>
#include <hip/hip_fp16.h>

// LightGCN on MI355X — round 4: two-phase binned CSR build (kills write amplification).
// Propagation stays in y-space: y_l = dinv .* x_l; z_{l+1} = unweighted in-gather of y_l;
// y_{l+1} = dinv^2 .* z; out = 0.25*(emb + sqrt(deg).*(y1+y2) + dinv.*z3).

#define N_NODES 150000
#define N_EDGES 2000000
#define DIM     64
#define NB_SCAN 586    // ceil(N_NODES / 256)
#define NBUCK   586    // buckets of 256 nodes (dst >> 8)

__global__ void zero_i32(int* __restrict__ p, int n) {
    int i = blockIdx.x * blockDim.x + threadIdx.x;
    if (i < n) p[i] = 0;
}

__global__ void hist_kernel(const int* __restrict__ dst, int* __restrict__ cnt) {
    int e = blockIdx.x * blockDim.x + threadIdx.x;
    if (e < N_EDGES) atomicAdd(&cnt[dst[e]], 1);
}

__global__ void scan_blocksum(const int* __restrict__ cnt, int* __restrict__ bsum) {
    __shared__ int s[256];
    int t = threadIdx.x;
    int i = blockIdx.x * 256 + t;
    s[t] = (i < N_NODES) ? cnt[i] : 0;
    __syncthreads();
    for (int off = 128; off > 0; off >>= 1) {
        if (t < off) s[t] += s[t + off];
        __syncthreads();
    }
    if (t == 0) bsum[blockIdx.x] = s[0];
}

__global__ __launch_bounds__(1024) void scan_bsum(int* __restrict__ bsum, int* __restrict__ ptrN) {
    __shared__ int s[1024];
    int t = threadIdx.x;
    int v = (t < NB_SCAN) ? bsum[t] : 0;
    s[t] = v;
    __syncthreads();
    for (int off = 1; off < 1024; off <<= 1) {
        int u = (t >= off) ? s[t - off] : 0;
        __syncthreads();
        s[t] += u;
        __syncthreads();
    }
    if (t < NB_SCAN) bsum[t] = s[t] - v;
    if (t == 1023) *ptrN = s[1023];
}

// Per-block exclusive scan + block offset -> ptr; dinv fused.
__global__ void scan_final(const int* __restrict__ cnt, const int* __restrict__ bsum,
                           int* __restrict__ ptr, float* __restrict__ dinv) {
    __shared__ int s[256];
    int t = threadIdx.x;
    int i = blockIdx.x * 256 + t;
    int v = (i < N_NODES) ? cnt[i] : 0;
    s[t] = v;
    __syncthreads();
    for (int off = 1; off < 256; off <<= 1) {
        int u = (t >= off) ? s[t - off] : 0;
        __syncthreads();
        s[t] += u;
        __syncthreads();
    }
    if (i < N_NODES) {
        ptr[i]  = bsum[blockIdx.x] + s[t] - v;
        dinv[i] = (v > 0) ? (1.0f / sqrtf((float)v)) : 0.0f;
    }
}

// Bucket cursors: one int per 64B line (stride 16) to spread atomic traffic across channels.
__global__ void init_bcur(const int* __restrict__ ptr, int* __restrict__ bcur) {
    int b = blockIdx.x * blockDim.x + threadIdx.x;
    if (b < NBUCK) bcur[b * 16] = ptr[b * 256];
}

// Phase 1: bin edges by dst>>8. Staged entry = (src<<8) | (dst&255), 4B.
// Appends within a bucket are sequential -> coalesced line writebacks.
__global__ void bin_edges(const int* __restrict__ src, const int* __restrict__ dst,
                          int* __restrict__ bcur, unsigned int* __restrict__ csr_tmp) {
    int e = blockIdx.x * blockDim.x + threadIdx.x;
    if (e < N_EDGES) {
        int s = src[e], d = dst[e];
        int pos = atomicAdd(&bcur[(d >> 8) * 16], 1);
        csr_tmp[pos] = ((unsigned int)s << 8) | (unsigned int)(d & 255);
    }
}

// Phase 2: one block per bucket; LDS cursors; place src into final CSR slots.
// Writes span ~13KB per block -> L2-resident, no amplification.
__global__ __launch_bounds__(256) void bucket_place(const int* __restrict__ ptr,
                                                    const unsigned int* __restrict__ csr_tmp,
                                                    int* __restrict__ csr_src) {
    __shared__ int lcur[256];
    int b = blockIdx.x;
    int t = threadIdx.x;
    int node0 = b * 256;
    int node = node0 + t;
    lcur[t] = ptr[node < N_NODES ? node : N_NODES];
    int beg = ptr[node0];
    int endn = node0 + 256; if (endn > N_NODES) endn = N_NODES;
    int end = ptr[endn];
    __syncthreads();
    for (int j = beg + t; j < end; j += 256) {
        unsigned int p = csr_tmp[j];
        int local = (int)(p & 255u);
        int s     = (int)(p >> 8);
        int pos = atomicAdd(&lcur[local], 1);
        csr_src[pos] = s;
    }
}

// y0 = dinv .* emb, stored fp16. One thread per 8 dims.
__global__ void init_y0(const float* __restrict__ emb, const float* __restrict__ dinv,
                        __half* __restrict__ y0) {
    int i = blockIdx.x * blockDim.x + threadIdx.x;
    if (i >= N_NODES * 8) return;
    int node = i >> 3, q = i & 7;
    float dv = dinv[node];
    size_t off = ((size_t)node << 6) + (q << 3);
    const float4 e0 = *reinterpret_cast<const float4*>(emb + off);
    const float4 e1 = *reinterpret_cast<const float4*>(emb + off + 4);
    uint4 o;
    __half2* oh = reinterpret_cast<__half2*>(&o);
    oh[0] = __float22half2_rn(make_float2(e0.x * dv, e0.y * dv));
    oh[1] = __float22half2_rn(make_float2(e0.z * dv, e0.w * dv));
    oh[2] = __float22half2_rn(make_float2(e1.x * dv, e1.y * dv));
    oh[3] = __float22half2_rn(make_float2(e1.z * dv, e1.w * dv));
    *reinterpret_cast<uint4*>(y0 + off) = o;
}

// One 8-lane group per node; lane q owns dims [8q, 8q+8).
__global__ void gather_layer_h(const int* __restrict__ ptr,
                               const int* __restrict__ csr_src,
                               const float* __restrict__ dinv,
                               const __half* __restrict__ yin,
                               __half* __restrict__ yout) {
    int tid = blockIdx.x * blockDim.x + threadIdx.x;
    int node = tid >> 3;
    int q    = tid & 7;
    if (node >= N_NODES) return;
    int beg = ptr[node], end = ptr[node + 1];
    float a[8] = {0.f, 0.f, 0.f, 0.f, 0.f, 0.f, 0.f, 0.f};
    for (int j = beg; j < end; ++j) {
        int sn = csr_src[j];
        const uint4 v = *reinterpret_cast<const uint4*>(yin + ((size_t)sn << 6) + (q << 3));
        const __half2* h = reinterpret_cast<const __half2*>(&v);
        float2 f;
        f = __half22float2(h[0]); a[0] += f.x; a[1] += f.y;
        f = __half22float2(h[1]); a[2] += f.x; a[3] += f.y;
        f = __half22float2(h[2]); a[4] += f.x; a[5] += f.y;
        f = __half22float2(h[3]); a[6] += f.x; a[7] += f.y;
    }
    float dv = dinv[node];
    float w = dv * dv;
    uint4 o;
    __half2* oh = reinterpret_cast<__half2*>(&o);
    oh[0] = __float22half2_rn(make_float2(a[0] * w, a[1] * w));
    oh[1] = __float22half2_rn(make_float2(a[2] * w, a[3] * w));
    oh[2] = __float22half2_rn(make_float2(a[4] * w, a[5] * w));
    oh[3] = __float22half2_rn(make_float2(a[6] * w, a[7] * w));
    *reinterpret_cast<uint4*>(yout + ((size_t)node << 6) + (q << 3)) = o;
}

// Final: z3 gather from y2; out = 0.25*(emb + sq*(y1+y2) + dinv*z3), fp32.
__global__ void gather_final_h(const int* __restrict__ ptr,
                               const int* __restrict__ csr_src,
                               const float* __restrict__ dinv,
                               const __half* __restrict__ y2,
                               const __half* __restrict__ y1,
                               const float* __restrict__ emb,
                               float* __restrict__ out) {
    int tid = blockIdx.x * blockDim.x + threadIdx.x;
    int node = tid >> 3;
    int q    = tid & 7;
    if (node >= N_NODES) return;
    int beg = ptr[node], end = ptr[node + 1];
    float a[8] = {0.f, 0.f, 0.f, 0.f, 0.f, 0.f, 0.f, 0.f};
    for (int j = beg; j < end; ++j) {
        int sn = csr_src[j];
        const uint4 v = *reinterpret_cast<const uint4*>(y2 + ((size_t)sn << 6) + (q << 3));
        const __half2* h = reinterpret_cast<const __half2*>(&v);
        float2 f;
        f = __half22float2(h[0]); a[0] += f.x; a[1] += f.y;
        f = __half22float2(h[1]); a[2] += f.x; a[3] += f.y;
        f = __half22float2(h[2]); a[4] += f.x; a[5] += f.y;
        f = __half22float2(h[3]); a[6] += f.x; a[7] += f.y;
    }
    float dv = dinv[node];
    float sq = (dv > 0.f) ? (1.0f / dv) : 0.0f;   // sqrt(deg), 0 for deg-0

    size_t off = ((size_t)node << 6) + (q << 3);
    const float4 e0 = *reinterpret_cast<const float4*>(emb + off);
    const float4 e1 = *reinterpret_cast<const float4*>(emb + off + 4);
    const uint4 v1 = *reinterpret_cast<const uint4*>(y1 + off);
    const uint4 v2 = *reinterpret_cast<const uint4*>(y2 + off);
    const __half2* h1 = reinterpret_cast<const __half2*>(&v1);
    const __half2* h2 = reinterpret_cast<const __half2*>(&v2);

    float e[8] = {e0.x, e0.y, e0.z, e0.w, e1.x, e1.y, e1.z, e1.w};
    float r[8];
#pragma unroll
    for (int k = 0; k < 4; ++k) {
        float2 f1 = __half22float2(h1[k]);
        float2 f2 = __half22float2(h2[k]);
        r[2 * k]     = 0.25f * (e[2 * k]     + sq * (f1.x + f2.x) + dv * a[2 * k]);
        r[2 * k + 1] = 0.25f * (e[2 * k + 1] + sq * (f1.y + f2.y) + dv * a[2 * k + 1]);
    }
    *reinterpret_cast<float4*>(out + off)     = make_float4(r[0], r[1], r[2], r[3]);
    *reinterpret_cast<float4*>(out + off + 4) = make_float4(r[4], r[5], r[6], r[7]);
}

extern "C" void kernel_launch(void* const* d_in, const int* in_sizes, int n_in,
                              void* d_out, int out_size, void* d_ws, size_t ws_size,
                              hipStream_t stream) {
    const int*   edge = (const int*)d_in[0];
    const int*   src  = edge;
    const int*   dst  = edge + N_EDGES;
    const float* emb  = (const float*)d_in[1];
    float* out = (float*)d_out;

    // Workspace layout (16B-aligned). Total ~75.4 MB.
    char* ws = (char*)d_ws;
    int*          ptr     = (int*)(ws + 0);          // N+1 ints
    int*          cnt     = (int*)(ws + 600064);     // N ints
    float*        dinv    = (float*)(ws + 1200064);  // N floats
    int*          bsum    = (int*)(ws + 1800064);    // NB_SCAN ints
    int*          bcur    = (int*)(ws + 1802432);    // NBUCK*16 ints (64B-strided cursors)
    int*          csr_src = (int*)(ws + 1839936);    // E ints
    unsigned int* csr_tmp = (unsigned int*)(ws + 9839936);   // E packed entries
    __half*       y0      = (__half*)(ws + 17839936); // N*D halves
    __half*       y1      = (__half*)(ws + 37039936); // N*D halves
    __half*       y2      = (__half*)(ws + 56239936); // N*D halves

    const int B = 256;

    // --- degree + ptr (scan) ---
    zero_i32<<<(N_NODES + B - 1) / B, B, 0, stream>>>(cnt, N_NODES);
    hist_kernel<<<(N_EDGES + B - 1) / B, B, 0, stream>>>(dst, cnt);
    scan_blocksum<<<NB_SCAN, B, 0, stream>>>(cnt, bsum);
    scan_bsum<<<1, 1024, 0, stream>>>(bsum, ptr + N_NODES);
    scan_final<<<NB_SCAN, B, 0, stream>>>(cnt, bsum, ptr, dinv);

    // --- two-phase CSR build ---
    init_bcur<<<(NBUCK + B - 1) / B, B, 0, stream>>>(ptr, bcur);
    bin_edges<<<(N_EDGES + B - 1) / B, B, 0, stream>>>(src, dst, bcur, csr_tmp);
    bucket_place<<<NBUCK, B, 0, stream>>>(ptr, csr_tmp, csr_src);

    // --- y0 = dinv .* emb ---
    const int NT8 = N_NODES * 8;
    init_y0<<<(NT8 + B - 1) / B, B, 0, stream>>>(emb, dinv, y0);

    // --- 3 propagation layers (8 lanes per node) ---
    const int nodeBlocks = (NT8 + B - 1) / B;
    gather_layer_h<<<nodeBlocks, B, 0, stream>>>(ptr, csr_src, dinv, y0, y1);
    gather_layer_h<<<nodeBlocks, B, 0, stream>>>(ptr, csr_src, dinv, y1, y2);
    gather_final_h<<<nodeBlocks, B, 0, stream>>>(ptr, csr_src, dinv, y2, y1, emb, out);
}

// Round 6
// 277.110 us; speedup vs baseline: 18.4769x; 1.7161x over previous
//
#include <hip/hip_runtime.h>
#include <hip/hip_fp16.h>

// LightGCN on MI355X — round 5: block-local binning (single-CU line ownership)
// + 4-deep software-pipelined gathers.
// y-space propagation: y_l = dinv .* x_l; z_{l+1} = unweighted in-gather of y_l;
// y_{l+1} = dinv^2 .* z; out = 0.25*(emb + sqrt(deg).*(y1+y2) + dinv.*z3).

#define N_NODES 150000
#define N_EDGES 2000000
#define DIM     64
#define NB_SCAN 586        // ceil(N_NODES / 256) for the ptr scan
#define NBUCK   256        // coarse buckets
#define BUCK_NODES 586     // nodes per bucket (586*256 = 150016 >= N_NODES)
#define EPB     8192       // edges per bin block
#define NBIN_BLOCKS ((N_EDGES + EPB - 1) / EPB)   // 245

__global__ void zero_i32(int* __restrict__ p, int n) {
    int i = blockIdx.x * blockDim.x + threadIdx.x;
    if (i < n) p[i] = 0;
}

__global__ void hist_kernel(const int* __restrict__ dst, int* __restrict__ cnt) {
    int e = blockIdx.x * blockDim.x + threadIdx.x;
    if (e < N_EDGES) atomicAdd(&cnt[dst[e]], 1);
}

__global__ void scan_blocksum(const int* __restrict__ cnt, int* __restrict__ bsum) {
    __shared__ int s[256];
    int t = threadIdx.x;
    int i = blockIdx.x * 256 + t;
    s[t] = (i < N_NODES) ? cnt[i] : 0;
    __syncthreads();
    for (int off = 128; off > 0; off >>= 1) {
        if (t < off) s[t] += s[t + off];
        __syncthreads();
    }
    if (t == 0) bsum[blockIdx.x] = s[0];
}

__global__ __launch_bounds__(1024) void scan_bsum(int* __restrict__ bsum, int* __restrict__ ptrN) {
    __shared__ int s[1024];
    int t = threadIdx.x;
    int v = (t < NB_SCAN) ? bsum[t] : 0;
    s[t] = v;
    __syncthreads();
    for (int off = 1; off < 1024; off <<= 1) {
        int u = (t >= off) ? s[t - off] : 0;
        __syncthreads();
        s[t] += u;
        __syncthreads();
    }
    if (t < NB_SCAN) bsum[t] = s[t] - v;
    if (t == 1023) *ptrN = s[1023];
}

__global__ void scan_final(const int* __restrict__ cnt, const int* __restrict__ bsum,
                           int* __restrict__ ptr, float* __restrict__ dinv) {
    __shared__ int s[256];
    int t = threadIdx.x;
    int i = blockIdx.x * 256 + t;
    int v = (i < N_NODES) ? cnt[i] : 0;
    s[t] = v;
    __syncthreads();
    for (int off = 1; off < 256; off <<= 1) {
        int u = (t >= off) ? s[t - off] : 0;
        __syncthreads();
        s[t] += u;
        __syncthreads();
    }
    if (i < N_NODES) {
        ptr[i]  = bsum[blockIdx.x] + s[t] - v;
        dinv[i] = (v > 0) ? (1.0f / sqrtf((float)v)) : 0.0f;
    }
}

// Bucket cursors: one int per 64B line (stride 16).
__global__ void init_bcur(const int* __restrict__ ptr, int* __restrict__ bcur) {
    int b = blockIdx.x * blockDim.x + threadIdx.x;
    if (b < NBUCK) {
        int n0 = b * BUCK_NODES;
        if (n0 > N_NODES) n0 = N_NODES;
        bcur[b * 16] = ptr[n0];
    }
}

// Phase 1: block-local two-pass binning. Each block owns EPB edges; one global
// atomicAdd per (block,bucket) reserves a contiguous allocation; every csr_tmp
// line is then written by exactly one CU. Entry = (src<<10) | (dst % 586).
__global__ __launch_bounds__(256) void bin_edges2(const int* __restrict__ src,
                                                  const int* __restrict__ dst,
                                                  int* __restrict__ bcur,
                                                  unsigned int* __restrict__ csr_tmp) {
    __shared__ int hist[NBUCK];
    __shared__ int lcur[NBUCK];
    int t = threadIdx.x;
    int e0 = blockIdx.x * EPB;
    int n = N_EDGES - e0; if (n > EPB) n = EPB;
    hist[t] = 0;
    __syncthreads();
    for (int i = t; i < n; i += 256) {
        int d = dst[e0 + i];
        atomicAdd(&hist[d / BUCK_NODES], 1);
    }
    __syncthreads();
    int h = hist[t];
    int base = (h > 0) ? atomicAdd(&bcur[t * 16], h) : 0;
    lcur[t] = base;
    __syncthreads();
    for (int i = t; i < n; i += 256) {
        int d = dst[e0 + i];
        int s = src[e0 + i];
        int b = d / BUCK_NODES;
        int pos = atomicAdd(&lcur[b], 1);
        csr_tmp[pos] = ((unsigned int)s << 10) | (unsigned int)(d - b * BUCK_NODES);
    }
}

// Phase 2: one block per coarse bucket; LDS cursors over 586 nodes from ptr;
// scatter confined to the bucket's ~30KB csr_src window (single CU).
__global__ __launch_bounds__(256) void bucket_place2(const int* __restrict__ ptr,
                                                     const unsigned int* __restrict__ csr_tmp,
                                                     int* __restrict__ csr_src) {
    __shared__ int lcur[BUCK_NODES];
    int b = blockIdx.x;
    int t = threadIdx.x;
    int node0 = b * BUCK_NODES;
    for (int i = t; i < BUCK_NODES; i += 256) {
        int nd = node0 + i;
        lcur[i] = ptr[nd < N_NODES ? nd : N_NODES];
    }
    int endn = node0 + BUCK_NODES; if (endn > N_NODES) endn = N_NODES;
    __syncthreads();
    int beg = ptr[node0 < N_NODES ? node0 : N_NODES];
    int end = ptr[endn];
    for (int j = beg + t; j < end; j += 256) {
        unsigned int p = csr_tmp[j];
        int local = (int)(p & 1023u);
        int s     = (int)(p >> 10);
        int pos = atomicAdd(&lcur[local], 1);
        csr_src[pos] = s;
    }
}

// y0 = dinv .* emb, stored fp16.
__global__ void init_y0(const float* __restrict__ emb, const float* __restrict__ dinv,
                        __half* __restrict__ y0) {
    int i = blockIdx.x * blockDim.x + threadIdx.x;
    if (i >= N_NODES * 8) return;
    int node = i >> 3, q = i & 7;
    float dv = dinv[node];
    size_t off = ((size_t)node << 6) + (q << 3);
    const float4 e0 = *reinterpret_cast<const float4*>(emb + off);
    const float4 e1 = *reinterpret_cast<const float4*>(emb + off + 4);
    uint4 o;
    __half2* oh = reinterpret_cast<__half2*>(&o);
    oh[0] = __float22half2_rn(make_float2(e0.x * dv, e0.y * dv));
    oh[1] = __float22half2_rn(make_float2(e0.z * dv, e0.w * dv));
    oh[2] = __float22half2_rn(make_float2(e1.x * dv, e1.y * dv));
    oh[3] = __float22half2_rn(make_float2(e1.z * dv, e1.w * dv));
    *reinterpret_cast<uint4*>(y0 + off) = o;
}

__device__ __forceinline__ void acc8(float* a, const uint4& v) {
    const __half2* h = reinterpret_cast<const __half2*>(&v);
    float2 f;
    f = __half22float2(h[0]); a[0] += f.x; a[1] += f.y;
    f = __half22float2(h[1]); a[2] += f.x; a[3] += f.y;
    f = __half22float2(h[2]); a[4] += f.x; a[5] += f.y;
    f = __half22float2(h[3]); a[6] += f.x; a[7] += f.y;
}

// One 8-lane group per node; lane q owns dims [8q, 8q+8). 4-deep pipelined loop.
__global__ void gather_layer_h(const int* __restrict__ ptr,
                               const int* __restrict__ csr_src,
                               const float* __restrict__ dinv,
                               const __half* __restrict__ yin,
                               __half* __restrict__ yout) {
    int tid = blockIdx.x * blockDim.x + threadIdx.x;
    int node = tid >> 3;
    int q    = tid & 7;
    if (node >= N_NODES) return;
    int beg = ptr[node], end = ptr[node + 1];
    float a[8] = {0.f, 0.f, 0.f, 0.f, 0.f, 0.f, 0.f, 0.f};
    int j = beg;
    for (; j + 4 <= end; j += 4) {
        int s0 = csr_src[j];
        int s1 = csr_src[j + 1];
        int s2 = csr_src[j + 2];
        int s3 = csr_src[j + 3];
        uint4 v0 = *reinterpret_cast<const uint4*>(yin + ((size_t)s0 << 6) + (q << 3));
        uint4 v1 = *reinterpret_cast<const uint4*>(yin + ((size_t)s1 << 6) + (q << 3));
        uint4 v2 = *reinterpret_cast<const uint4*>(yin + ((size_t)s2 << 6) + (q << 3));
        uint4 v3 = *reinterpret_cast<const uint4*>(yin + ((size_t)s3 << 6) + (q << 3));
        acc8(a, v0); acc8(a, v1); acc8(a, v2); acc8(a, v3);
    }
    for (; j < end; ++j) {
        int sn = csr_src[j];
        uint4 v = *reinterpret_cast<const uint4*>(yin + ((size_t)sn << 6) + (q << 3));
        acc8(a, v);
    }
    float dv = dinv[node];
    float w = dv * dv;
    uint4 o;
    __half2* oh = reinterpret_cast<__half2*>(&o);
    oh[0] = __float22half2_rn(make_float2(a[0] * w, a[1] * w));
    oh[1] = __float22half2_rn(make_float2(a[2] * w, a[3] * w));
    oh[2] = __float22half2_rn(make_float2(a[4] * w, a[5] * w));
    oh[3] = __float22half2_rn(make_float2(a[6] * w, a[7] * w));
    *reinterpret_cast<uint4*>(yout + ((size_t)node << 6) + (q << 3)) = o;
}

// Final: z3 gather from y2; out = 0.25*(emb + sq*(y1+y2) + dinv*z3), fp32.
__global__ void gather_final_h(const int* __restrict__ ptr,
                               const int* __restrict__ csr_src,
                               const float* __restrict__ dinv,
                               const __half* __restrict__ y2,
                               const __half* __restrict__ y1,
                               const float* __restrict__ emb,
                               float* __restrict__ out) {
    int tid = blockIdx.x * blockDim.x + threadIdx.x;
    int node = tid >> 3;
    int q    = tid & 7;
    if (node >= N_NODES) return;
    int beg = ptr[node], end = ptr[node + 1];
    float a[8] = {0.f, 0.f, 0.f, 0.f, 0.f, 0.f, 0.f, 0.f};
    int j = beg;
    for (; j + 4 <= end; j += 4) {
        int s0 = csr_src[j];
        int s1 = csr_src[j + 1];
        int s2 = csr_src[j + 2];
        int s3 = csr_src[j + 3];
        uint4 v0 = *reinterpret_cast<const uint4*>(y2 + ((size_t)s0 << 6) + (q << 3));
        uint4 v1 = *reinterpret_cast<const uint4*>(y2 + ((size_t)s1 << 6) + (q << 3));
        uint4 v2 = *reinterpret_cast<const uint4*>(y2 + ((size_t)s2 << 6) + (q << 3));
        uint4 v3 = *reinterpret_cast<const uint4*>(y2 + ((size_t)s3 << 6) + (q << 3));
        acc8(a, v0); acc8(a, v1); acc8(a, v2); acc8(a, v3);
    }
    for (; j < end; ++j) {
        int sn = csr_src[j];
        uint4 v = *reinterpret_cast<const uint4*>(y2 + ((size_t)sn << 6) + (q << 3));
        acc8(a, v);
    }
    float dv = dinv[node];
    float sq = (dv > 0.f) ? (1.0f / dv) : 0.0f;   // sqrt(deg), 0 for deg-0

    size_t off = ((size_t)node << 6) + (q << 3);
    const float4 e0 = *reinterpret_cast<const float4*>(emb + off);
    const float4 e1 = *reinterpret_cast<const float4*>(emb + off + 4);
    const uint4 v1 = *reinterpret_cast<const uint4*>(y1 + off);
    const uint4 v2 = *reinterpret_cast<const uint4*>(y2 + off);
    const __half2* h1 = reinterpret_cast<const __half2*>(&v1);
    const __half2* h2 = reinterpret_cast<const __half2*>(&v2);

    float e[8] = {e0.x, e0.y, e0.z, e0.w, e1.x, e1.y, e1.z, e1.w};
    float r[8];
#pragma unroll
    for (int k = 0; k < 4; ++k) {
        float2 f1 = __half22float2(h1[k]);
        float2 f2 = __half22float2(h2[k]);
        r[2 * k]     = 0.25f * (e[2 * k]     + sq * (f1.x + f2.x) + dv * a[2 * k]);
        r[2 * k + 1] = 0.25f * (e[2 * k + 1] + sq * (f1.y + f2.y) + dv * a[2 * k + 1]);
    }
    *reinterpret_cast<float4*>(out + off)     = make_float4(r[0], r[1], r[2], r[3]);
    *reinterpret_cast<float4*>(out + off + 4) = make_float4(r[4], r[5], r[6], r[7]);
}

extern "C" void kernel_launch(void* const* d_in, const int* in_sizes, int n_in,
                              void* d_out, int out_size, void* d_ws, size_t ws_size,
                              hipStream_t stream) {
    const int*   edge = (const int*)d_in[0];
    const int*   src  = edge;
    const int*   dst  = edge + N_EDGES;
    const float* emb  = (const float*)d_in[1];
    float* out = (float*)d_out;

    // Workspace layout. Total ~75.4 MB.
    char* ws = (char*)d_ws;
    int*          ptr     = (int*)(ws + 0);            // N+1 ints
    int*          cnt     = (int*)(ws + 600064);       // N ints
    float*        dinv    = (float*)(ws + 1200064);    // N floats
    int*          bsum    = (int*)(ws + 1800064);      // NB_SCAN ints
    int*          bcur    = (int*)(ws + 1802432);      // NBUCK*16 ints (64B-strided)
    int*          csr_src = (int*)(ws + 1818816);      // E ints
    unsigned int* csr_tmp = (unsigned int*)(ws + 9818816);   // E packed entries
    __half*       y0      = (__half*)(ws + 17818880);  // N*D halves (128B aligned)
    __half*       y1      = (__half*)(ws + 37018880);  // N*D halves
    __half*       y2      = (__half*)(ws + 56218880);  // N*D halves

    const int B = 256;

    // --- degree + ptr (scan) ---
    zero_i32<<<(N_NODES + B - 1) / B, B, 0, stream>>>(cnt, N_NODES);
    hist_kernel<<<(N_EDGES + B - 1) / B, B, 0, stream>>>(dst, cnt);
    scan_blocksum<<<NB_SCAN, B, 0, stream>>>(cnt, bsum);
    scan_bsum<<<1, 1024, 0, stream>>>(bsum, ptr + N_NODES);
    scan_final<<<NB_SCAN, B, 0, stream>>>(cnt, bsum, ptr, dinv);

    // --- two-phase CSR build (block-local allocations) ---
    init_bcur<<<1, NBUCK, 0, stream>>>(ptr, bcur);
    bin_edges2<<<NBIN_BLOCKS, B, 0, stream>>>(src, dst, bcur, csr_tmp);
    bucket_place2<<<NBUCK, B, 0, stream>>>(ptr, csr_tmp, csr_src);

    // --- y0 = dinv .* emb ---
    const int NT8 = N_NODES * 8;
    init_y0<<<(NT8 + B - 1) / B, B, 0, stream>>>(emb, dinv, y0);

    // --- 3 propagation layers (8 lanes per node) ---
    const int nodeBlocks = (NT8 + B - 1) / B;
    gather_layer_h<<<nodeBlocks, B, 0, stream>>>(ptr, csr_src, dinv, y0, y1);
    gather_layer_h<<<nodeBlocks, B, 0, stream>>>(ptr, csr_src, dinv, y1, y2);
    gather_final_h<<<nodeBlocks, B, 0, stream>>>(ptr, csr_src, dinv, y2, y1, emb, out);
}

// Round 7
// 197.414 us; speedup vs baseline: 25.9360x; 1.4037x over previous
//
#include <hip/hip_runtime.h>
#include <hip/hip_fp16.h>

// LightGCN on MI355X — round 6: histogram-free CSR build.
// Fixed-capacity buckets (dst>>9) let binning run without ptr; per-node degree,
// ptr, dinv are derived inside each bucket via LDS hist + LDS scan.
// y-space propagation: y_l = dinv .* x_l; z_{l+1} = unweighted in-gather of y_l;
// y_{l+1} = dinv^2 .* z; out = 0.25*(emb + sqrt(deg).*(y1+y2) + dinv.*z3).

#define N_NODES 150000
#define N_EDGES 2000000
#define DIM     64
#define BUCK_SHIFT 9
#define BUCK_NODES 512                    // nodes per bucket
#define NBUCK   293                       // ceil(150000/512); 293*512 = 150016
#define CAP     8192                      // staged capacity per bucket (mean 6826, +16 sigma)
#define EPB     8192                      // edges per bin block
#define NBIN_BLOCKS ((N_EDGES + EPB - 1) / EPB)   // 245

// bcur[b*16] = b*CAP  (64B-strided cursors, no ptr dependency)
__global__ void init_bcur(int* __restrict__ bcur) {
    int b = blockIdx.x * blockDim.x + threadIdx.x;
    if (b < NBUCK) bcur[b * 16] = b * CAP;
}

// Phase 1: block-local two-pass binning. Each block owns EPB edges; LDS hist over
// 293 buckets; one global atomicAdd per (block,bucket) reserves a contiguous range;
// place pass writes (src<<9)|(dst&511) — every csr_tmp line written by one CU.
__global__ __launch_bounds__(256) void bin_edges3(const int* __restrict__ src,
                                                  const int* __restrict__ dst,
                                                  int* __restrict__ bcur,
                                                  unsigned int* __restrict__ csr_tmp) {
    __shared__ int hist[NBUCK];
    __shared__ int lcur[NBUCK];
    int t = threadIdx.x;
    int e0 = blockIdx.x * EPB;
    int n = N_EDGES - e0; if (n > EPB) n = EPB;
    for (int i = t; i < NBUCK; i += 256) hist[i] = 0;
    __syncthreads();
    for (int i = t; i < n; i += 256) {
        atomicAdd(&hist[dst[e0 + i] >> BUCK_SHIFT], 1);
    }
    __syncthreads();
    for (int i = t; i < NBUCK; i += 256) {
        int h = hist[i];
        lcur[i] = (h > 0) ? atomicAdd(&bcur[i * 16], h) : 0;
    }
    __syncthreads();
    for (int i = t; i < n; i += 256) {
        int d = dst[e0 + i];
        int s = src[e0 + i];
        int b = d >> BUCK_SHIFT;
        int pos = atomicAdd(&lcur[b], 1);
        csr_tmp[pos] = ((unsigned int)s << BUCK_SHIFT) | (unsigned int)(d & (BUCK_NODES - 1));
    }
}

// Tiny scan over the 293 bucket counts -> bucket bases; ptr[N] = total (= E).
__global__ __launch_bounds__(512) void bucket_scan(const int* __restrict__ bcur,
                                                   int* __restrict__ bbase,
                                                   int* __restrict__ ptrN) {
    __shared__ int s[512];
    int t = threadIdx.x;
    int c = (t < NBUCK) ? (bcur[t * 16] - t * CAP) : 0;
    s[t] = c;
    __syncthreads();
    for (int off = 1; off < 512; off <<= 1) {
        int u = (t >= off) ? s[t - off] : 0;
        __syncthreads();
        s[t] += u;
        __syncthreads();
    }
    if (t < NBUCK) bbase[t] = s[t] - c;   // exclusive
    if (t == 511) *ptrN = s[511];         // = N_EDGES
}

// Phase 2: one block per bucket. LDS hist over the 512 local nodes, LDS scan ->
// ptr/dinv for those nodes, then place edges via LDS cursors into the bucket's
// contiguous csr_src window (single CU, L2-resident).
__global__ __launch_bounds__(256) void bucket_place3(const int* __restrict__ bcur,
                                                     const int* __restrict__ bbase,
                                                     const unsigned int* __restrict__ csr_tmp,
                                                     int* __restrict__ csr_src,
                                                     int* __restrict__ ptr,
                                                     float* __restrict__ dinv) {
    __shared__ int hist[BUCK_NODES];
    __shared__ int scn[BUCK_NODES];
    __shared__ int lcur[BUCK_NODES];
    int b = blockIdx.x;
    int t = threadIdx.x;
    int cntb = bcur[b * 16] - b * CAP;
    int base = bbase[b];
    int tmp0 = b * CAP;

    hist[t] = 0; hist[t + 256] = 0;
    __syncthreads();
    for (int j = t; j < cntb; j += 256)
        atomicAdd(&hist[csr_tmp[tmp0 + j] & (BUCK_NODES - 1)], 1);
    __syncthreads();

    // inclusive scan of 512 counts: two 256-segments in parallel + carry
    int c0 = hist[t], c1 = hist[t + 256];
    scn[t] = c0; scn[t + 256] = c1;
    __syncthreads();
    for (int off = 1; off < 256; off <<= 1) {
        int u0 = (t >= off) ? scn[t - off] : 0;
        int u1 = (t >= off) ? scn[256 + t - off] : 0;
        __syncthreads();
        scn[t] += u0; scn[256 + t] += u1;
        __syncthreads();
    }
    int carry = scn[255];
    int ex0 = scn[t] - c0;               // exclusive local offsets
    int ex1 = carry + scn[256 + t] - c1;

    int node0 = b * BUCK_NODES;
    int nd0 = node0 + t, nd1 = node0 + 256 + t;
    if (nd0 < N_NODES) {
        ptr[nd0]  = base + ex0;
        dinv[nd0] = (c0 > 0) ? (1.0f / sqrtf((float)c0)) : 0.0f;
    }
    if (nd1 < N_NODES) {
        ptr[nd1]  = base + ex1;
        dinv[nd1] = (c1 > 0) ? (1.0f / sqrtf((float)c1)) : 0.0f;
    }
    lcur[t] = base + ex0; lcur[t + 256] = base + ex1;
    __syncthreads();

    for (int j = t; j < cntb; j += 256) {
        unsigned int p = csr_tmp[tmp0 + j];
        int local = (int)(p & (BUCK_NODES - 1));
        int pos = atomicAdd(&lcur[local], 1);
        csr_src[pos] = (int)(p >> BUCK_SHIFT);
    }
}

// y0 = dinv .* emb, stored fp16.
__global__ void init_y0(const float* __restrict__ emb, const float* __restrict__ dinv,
                        __half* __restrict__ y0) {
    int i = blockIdx.x * blockDim.x + threadIdx.x;
    if (i >= N_NODES * 8) return;
    int node = i >> 3, q = i & 7;
    float dv = dinv[node];
    size_t off = ((size_t)node << 6) + (q << 3);
    const float4 e0 = *reinterpret_cast<const float4*>(emb + off);
    const float4 e1 = *reinterpret_cast<const float4*>(emb + off + 4);
    uint4 o;
    __half2* oh = reinterpret_cast<__half2*>(&o);
    oh[0] = __float22half2_rn(make_float2(e0.x * dv, e0.y * dv));
    oh[1] = __float22half2_rn(make_float2(e0.z * dv, e0.w * dv));
    oh[2] = __float22half2_rn(make_float2(e1.x * dv, e1.y * dv));
    oh[3] = __float22half2_rn(make_float2(e1.z * dv, e1.w * dv));
    *reinterpret_cast<uint4*>(y0 + off) = o;
}

__device__ __forceinline__ void acc8(float* a, const uint4& v) {
    const __half2* h = reinterpret_cast<const __half2*>(&v);
    float2 f;
    f = __half22float2(h[0]); a[0] += f.x; a[1] += f.y;
    f = __half22float2(h[1]); a[2] += f.x; a[3] += f.y;
    f = __half22float2(h[2]); a[4] += f.x; a[5] += f.y;
    f = __half22float2(h[3]); a[6] += f.x; a[7] += f.y;
}

// One 8-lane group per node; lane q owns dims [8q, 8q+8). 4-deep pipelined loop.
__global__ void gather_layer_h(const int* __restrict__ ptr,
                               const int* __restrict__ csr_src,
                               const float* __restrict__ dinv,
                               const __half* __restrict__ yin,
                               __half* __restrict__ yout) {
    int tid = blockIdx.x * blockDim.x + threadIdx.x;
    int node = tid >> 3;
    int q    = tid & 7;
    if (node >= N_NODES) return;
    int beg = ptr[node], end = ptr[node + 1];
    float a[8] = {0.f, 0.f, 0.f, 0.f, 0.f, 0.f, 0.f, 0.f};
    int j = beg;
    for (; j + 4 <= end; j += 4) {
        int s0 = csr_src[j];
        int s1 = csr_src[j + 1];
        int s2 = csr_src[j + 2];
        int s3 = csr_src[j + 3];
        uint4 v0 = *reinterpret_cast<const uint4*>(yin + ((size_t)s0 << 6) + (q << 3));
        uint4 v1 = *reinterpret_cast<const uint4*>(yin + ((size_t)s1 << 6) + (q << 3));
        uint4 v2 = *reinterpret_cast<const uint4*>(yin + ((size_t)s2 << 6) + (q << 3));
        uint4 v3 = *reinterpret_cast<const uint4*>(yin + ((size_t)s3 << 6) + (q << 3));
        acc8(a, v0); acc8(a, v1); acc8(a, v2); acc8(a, v3);
    }
    for (; j < end; ++j) {
        int sn = csr_src[j];
        uint4 v = *reinterpret_cast<const uint4*>(yin + ((size_t)sn << 6) + (q << 3));
        acc8(a, v);
    }
    float dv = dinv[node];
    float w = dv * dv;
    uint4 o;
    __half2* oh = reinterpret_cast<__half2*>(&o);
    oh[0] = __float22half2_rn(make_float2(a[0] * w, a[1] * w));
    oh[1] = __float22half2_rn(make_float2(a[2] * w, a[3] * w));
    oh[2] = __float22half2_rn(make_float2(a[4] * w, a[5] * w));
    oh[3] = __float22half2_rn(make_float2(a[6] * w, a[7] * w));
    *reinterpret_cast<uint4*>(yout + ((size_t)node << 6) + (q << 3)) = o;
}

// Final: z3 gather from y2; out = 0.25*(emb + sq*(y1+y2) + dinv*z3), fp32.
__global__ void gather_final_h(const int* __restrict__ ptr,
                               const int* __restrict__ csr_src,
                               const float* __restrict__ dinv,
                               const __half* __restrict__ y2,
                               const __half* __restrict__ y1,
                               const float* __restrict__ emb,
                               float* __restrict__ out) {
    int tid = blockIdx.x * blockDim.x + threadIdx.x;
    int node = tid >> 3;
    int q    = tid & 7;
    if (node >= N_NODES) return;
    int beg = ptr[node], end = ptr[node + 1];
    float a[8] = {0.f, 0.f, 0.f, 0.f, 0.f, 0.f, 0.f, 0.f};
    int j = beg;
    for (; j + 4 <= end; j += 4) {
        int s0 = csr_src[j];
        int s1 = csr_src[j + 1];
        int s2 = csr_src[j + 2];
        int s3 = csr_src[j + 3];
        uint4 v0 = *reinterpret_cast<const uint4*>(y2 + ((size_t)s0 << 6) + (q << 3));
        uint4 v1 = *reinterpret_cast<const uint4*>(y2 + ((size_t)s1 << 6) + (q << 3));
        uint4 v2 = *reinterpret_cast<const uint4*>(y2 + ((size_t)s2 << 6) + (q << 3));
        uint4 v3 = *reinterpret_cast<const uint4*>(y2 + ((size_t)s3 << 6) + (q << 3));
        acc8(a, v0); acc8(a, v1); acc8(a, v2); acc8(a, v3);
    }
    for (; j < end; ++j) {
        int sn = csr_src[j];
        uint4 v = *reinterpret_cast<const uint4*>(y2 + ((size_t)sn << 6) + (q << 3));
        acc8(a, v);
    }
    float dv = dinv[node];
    float sq = (dv > 0.f) ? (1.0f / dv) : 0.0f;   // sqrt(deg), 0 for deg-0

    size_t off = ((size_t)node << 6) + (q << 3);
    const float4 e0 = *reinterpret_cast<const float4*>(emb + off);
    const float4 e1 = *reinterpret_cast<const float4*>(emb + off + 4);
    const uint4 v1 = *reinterpret_cast<const uint4*>(y1 + off);
    const uint4 v2 = *reinterpret_cast<const uint4*>(y2 + off);
    const __half2* h1 = reinterpret_cast<const __half2*>(&v1);
    const __half2* h2 = reinterpret_cast<const __half2*>(&v2);

    float e[8] = {e0.x, e0.y, e0.z, e0.w, e1.x, e1.y, e1.z, e1.w};
    float r[8];
#pragma unroll
    for (int k = 0; k < 4; ++k) {
        float2 f1 = __half22float2(h1[k]);
        float2 f2 = __half22float2(h2[k]);
        r[2 * k]     = 0.25f * (e[2 * k]     + sq * (f1.x + f2.x) + dv * a[2 * k]);
        r[2 * k + 1] = 0.25f * (e[2 * k + 1] + sq * (f1.y + f2.y) + dv * a[2 * k + 1]);
    }
    *reinterpret_cast<float4*>(out + off)     = make_float4(r[0], r[1], r[2], r[3]);
    *reinterpret_cast<float4*>(out + off + 4) = make_float4(r[4], r[5], r[6], r[7]);
}

extern "C" void kernel_launch(void* const* d_in, const int* in_sizes, int n_in,
                              void* d_out, int out_size, void* d_ws, size_t ws_size,
                              hipStream_t stream) {
    const int*   edge = (const int*)d_in[0];
    const int*   src  = edge;
    const int*   dst  = edge + N_EDGES;
    const float* emb  = (const float*)d_in[1];
    float* out = (float*)d_out;

    // Workspace layout (64B-aligned). Total ~76.4 MB.
    char* ws = (char*)d_ws;
    int*          ptr     = (int*)(ws + 0);            // N+1 ints
    float*        dinv    = (float*)(ws + 600064);     // N floats
    int*          bcur    = (int*)(ws + 1200064);      // NBUCK*16 ints (64B-strided)
    int*          bbase   = (int*)(ws + 1218816);      // NBUCK ints
    int*          csr_src = (int*)(ws + 1220096);      // E ints
    unsigned int* csr_tmp = (unsigned int*)(ws + 9220096);   // NBUCK*CAP entries
    __half*       y0      = (__half*)(ws + 18821120);  // N*D halves
    __half*       y1      = (__half*)(ws + 38021120);  // N*D halves
    __half*       y2      = (__half*)(ws + 57221120);  // N*D halves

    const int B = 256;

    // --- histogram-free CSR build ---
    init_bcur<<<2, 256, 0, stream>>>(bcur);
    bin_edges3<<<NBIN_BLOCKS, B, 0, stream>>>(src, dst, bcur, csr_tmp);
    bucket_scan<<<1, 512, 0, stream>>>(bcur, bbase, ptr + N_NODES);
    bucket_place3<<<NBUCK, B, 0, stream>>>(bcur, bbase, csr_tmp, csr_src, ptr, dinv);

    // --- y0 = dinv .* emb ---
    const int NT8 = N_NODES * 8;
    init_y0<<<(NT8 + B - 1) / B, B, 0, stream>>>(emb, dinv, y0);

    // --- 3 propagation layers (8 lanes per node) ---
    const int nodeBlocks = (NT8 + B - 1) / B;
    gather_layer_h<<<nodeBlocks, B, 0, stream>>>(ptr, csr_src, dinv, y0, y1);
    gather_layer_h<<<nodeBlocks, B, 0, stream>>>(ptr, csr_src, dinv, y1, y2);
    gather_final_h<<<nodeBlocks, B, 0, stream>>>(ptr, csr_src, dinv, y2, y1, emb, out);
}